// Round 25
// baseline (63.613 us; speedup 1.0000x reference)
//
#include <hip/hip_runtime.h>
#include <hip/hip_fp16.h>
#include <stdint.h>

#define N_FEAT 32
#define NPB_SHIFT 8                   // 256 nodes per bin (best config, R17/R21)
#define NPB (1 << NPB_SHIFT)
#define MAX_BINS 512
#define BINSLOT 8192                  // fixed binstream slots per bin (avg load ~4096)
#define OVF_CAP 65536                 // overflow safety net (unused for this input)
#define PART_THREADS 1024
#define PART_CHUNK 3072               // edges per partition block (LDS-cached)
#define FUSE_THREADS 1024

__device__ inline float hconv(unsigned short v) {
    union { unsigned short u; __half h; } c; c.u = v;
    return __half2float(c.h);
}
__device__ inline unsigned short f2h(float v) {
    union { __half h; unsigned short u; } c; c.h = __float2half_rn(v);
    return c.u;
}

// ---------- fallback path (baseline, known-correct, ~177us) ----------
__global__ void zero_out(float* __restrict__ out, int n) {
    int i = blockIdx.x * blockDim.x + threadIdx.x;
    if (i < n) out[i] = 0.0f;
}

__global__ void mp_scatter_add(const float* __restrict__ x,
                               const int* __restrict__ src,
                               const int* __restrict__ dst,
                               float* __restrict__ out,
                               int n_edges) {
    long long tid = (long long)blockIdx.x * blockDim.x + threadIdx.x;
    long long total = (long long)n_edges * N_FEAT;
    if (tid >= total) return;
    int e = (int)(tid >> 5);
    int f = (int)(tid & 31);
    atomicAdd(&out[(long long)dst[e] * N_FEAT + f],
              x[(long long)src[e] * N_FEAT + f]);
}

// ---------- fast path ----------
// R15 lesson: no cooperative grid.sync() fusion (XCD coherence kills caching).
// R16/R17/R21/R24 lessons: sort machinery, gather issue-count, occupancy all
// NOT the fused-kernel cost. Remaining term: gather BYTES (205 MB vs 12.8 MB
// table that misses the 4 MB/XCD L2). R25: gather from an fp16 copy of x —
// halves traffic, doubles L2 residency. Accumulation stays f32.
// Precision: |x|<=5.2, fp16 RTN err <= 2^-11 rel -> worst node sum err ~0.11
// << 0.48 threshold.

// K-1: convert x to fp16 table (write-once stream, ~19 MB traffic).
__global__ void convert_half(const float4* __restrict__ x4,
                             ushort4* __restrict__ xh4, int n4) {
    int stride = gridDim.x * blockDim.x;
    for (int i = blockIdx.x * blockDim.x + threadIdx.x; i < n4; i += stride) {
        float4 v = x4[i];
        ushort4 o;
        o.x = f2h(v.x); o.y = f2h(v.y); o.z = f2h(v.z); o.w = f2h(v.w);
        xh4[i] = o;
    }
}

// K0: init per-bin cursors + overflow counter (ws is poisoned; must re-init).
__global__ void init_bins(int* __restrict__ bincur, int nbins,
                          int* __restrict__ ovf_cnt) {
    int t = blockIdx.x * blockDim.x + threadIdx.x;
    if (t < nbins) bincur[t] = t * BINSLOT;
    if (t == nbins) *ovf_cnt = 0;
}

// K1: partition edges into fixed-capacity bins (LDS-cached chunk; src/dst
// read from HBM exactly once).
__global__ void __launch_bounds__(PART_THREADS)
partition_bins(const int* __restrict__ src, const int* __restrict__ dst,
               int n_edges, int* __restrict__ bincur,
               uint32_t* __restrict__ binstream,
               uint32_t* __restrict__ ovf_src, uint32_t* __restrict__ ovf_dst,
               int* __restrict__ ovf_cnt, int nbins) {
    __shared__ uint32_t epack[PART_CHUNK];   // (src<<8)|dst_local
    __shared__ uint16_t ebin[PART_CHUNK];    // bin id
    __shared__ int cnt[MAX_BINS];
    __shared__ int base[MAX_BINS];
    const int beg = blockIdx.x * PART_CHUNK;
    const int end = min(beg + PART_CHUNK, n_edges);
    const int m = end - beg;

    for (int b = threadIdx.x; b < nbins; b += blockDim.x) cnt[b] = 0;
    __syncthreads();
    for (int i = threadIdx.x; i < m; i += blockDim.x) {
        int d = dst[beg + i];
        int s = src[beg + i];
        int b = d >> NPB_SHIFT;
        epack[i] = ((uint32_t)s << NPB_SHIFT) | (uint32_t)(d & (NPB - 1));
        ebin[i]  = (uint16_t)b;
        atomicAdd(&cnt[b], 1);               // LDS atomic
    }
    __syncthreads();
    for (int b = threadIdx.x; b < nbins; b += blockDim.x) {
        int c = cnt[b];
        base[b] = c ? atomicAdd(&bincur[b], c) : 0;   // one global atomic each
        cnt[b] = 0;                                   // becomes local cursor
    }
    __syncthreads();
    for (int i = threadIdx.x; i < m; i += blockDim.x) {
        int b = ebin[i];
        uint32_t e = epack[i];
        int p = base[b] + atomicAdd(&cnt[b], 1);      // LDS atomic
        if (p < (b + 1) * BINSLOT) {
            binstream[p] = e;                         // block-private segment
        } else {                                      // overflow net (never hit here)
            int o = atomicAdd(ovf_cnt, 1);
            if (o < OVF_CAP) {
                ovf_src[o] = e >> NPB_SHIFT;
                ovf_dst[o] = ((uint32_t)b << NPB_SHIFT) | (e & (NPB - 1));
            }
        }
    }
}

// K2 (FUSED sort+aggregate): one block per 256-node bin. Gathers from the
// fp16 table: row = 32 halves = 64B = 8 lanes x ushort4. f32 accumulation.
__global__ void __launch_bounds__(FUSE_THREADS)
binsort_aggregate(const uint32_t* __restrict__ binstream,
                  const int* __restrict__ bincur,
                  const uint32_t* __restrict__ ovf_src,
                  const uint32_t* __restrict__ ovf_dst,
                  const int* __restrict__ ovf_cnt,
                  const ushort4* __restrict__ xh4,
                  float* __restrict__ out, int n_nodes) {
    __shared__ uint32_t ebuf[BINSLOT];     // 32 KB: raw bin edges (single global read)
    __shared__ uint32_t srtd[BINSLOT];     // 32 KB: rank-sorted src ids
    __shared__ int hist[NPB];              // counts -> exclusive per-node start
    __shared__ int sc[NPB];                // inclusive per-node end
    __shared__ int lcur[NPB];
    __shared__ int wsum[4];                // per-wave scan totals
    const int b = blockIdx.x;
    const int n0 = b << NPB_SHIFT;
    const int nn = min(NPB, n_nodes - n0);
    const int binstart = b * BINSLOT;
    const int cnt = min(bincur[b] - binstart, BINSLOT);
    const int novf = *ovf_cnt;             // 0 in practice
    const int t = threadIdx.x;
    const int g  = t >> 5;                 // group 0..31
    const int l  = t & 31;
    const int e4 = l >> 3;                 // edge slot 0..3
    const int q  = l & 7;                  // feature quad 0..7
    float4* __restrict__ out4 = (float4*)out;

    if (t < NPB) { hist[t] = 0; lcur[t] = 0; }
    __syncthreads();
    for (int i = t; i < cnt; i += FUSE_THREADS) {
        uint32_t e = __builtin_nontemporal_load(&binstream[binstart + i]); // NT stream
        ebuf[i] = e;
        atomicAdd(&hist[e & (NPB - 1)], 1);
    }
    __syncthreads();

    // wave-shfl inclusive scan over hist[0..255] (4 full waves)
    int vin = 0, val = 0;
    if (t < NPB) {
        vin = hist[t];
        val = vin;
#pragma unroll
        for (int off = 1; off < 64; off <<= 1) {
            int u = __shfl_up(val, (unsigned)off, 64);
            if ((t & 63) >= off) val += u;
        }
        if ((t & 63) == 63) wsum[t >> 6] = val;
    }
    __syncthreads();
    if (t < NPB) {
        int w = t >> 6, prefix = 0;
#pragma unroll
        for (int k = 0; k < 3; ++k) if (k < w) prefix += wsum[k];
        val += prefix;
        sc[t] = val;                       // inclusive end
        hist[t] = val - vin;               // exclusive start
    }
    __syncthreads();

    for (int i = t; i < cnt; i += FUSE_THREADS) {
        uint32_t e = ebuf[i];              // LDS re-read (not global)
        int dl = (int)(e & (NPB - 1));
        int p = hist[dl] + atomicAdd(&lcur[dl], 1);
        srtd[p] = e >> NPB_SHIFT;          // src id
    }
    __syncthreads();

    for (int dl = g; dl < nn; dl += 32) {
        int beg = hist[dl];
        int end = sc[dl];
        float4 acc = make_float4(0.f, 0.f, 0.f, 0.f);
        int i = beg;
        // unmasked 16-wide main loop (fp16 rows, 8B/lane)
        for (; i + 16 <= end; i += 16) {
#pragma unroll
            for (int k = 0; k < 4; ++k) {
                uint32_t s = srtd[i + k * 4 + e4];
                ushort4 u = xh4[(size_t)s * (N_FEAT / 4) + q];
                acc.x += hconv(u.x); acc.y += hconv(u.y);
                acc.z += hconv(u.z); acc.w += hconv(u.w);
            }
        }
        // 4-wide tail
        for (; i < end; i += 4) {
            int j = i + e4;
            bool ok = j < end;
            uint32_t s = srtd[ok ? j : i];
            ushort4 u = xh4[(size_t)s * (N_FEAT / 4) + q];
            float m = ok ? 1.0f : 0.0f;
            acc.x = fmaf(hconv(u.x), m, acc.x);
            acc.y = fmaf(hconv(u.y), m, acc.y);
            acc.z = fmaf(hconv(u.z), m, acc.z);
            acc.w = fmaf(hconv(u.w), m, acc.w);
        }
        acc.x += __shfl_xor(acc.x, 8);  acc.y += __shfl_xor(acc.y, 8);
        acc.z += __shfl_xor(acc.z, 8);  acc.w += __shfl_xor(acc.w, 8);
        acc.x += __shfl_xor(acc.x, 16); acc.y += __shfl_xor(acc.y, 16);
        acc.z += __shfl_xor(acc.z, 16); acc.w += __shfl_xor(acc.w, 16);
        if (e4 == 0) {
            for (int i2 = 0; i2 < novf; ++i2) {        // novf==0 normally
                uint32_t od = ovf_dst[i2];
                if ((int)(od >> NPB_SHIFT) == b && (int)(od & (NPB - 1)) == dl) {
                    ushort4 u = xh4[(size_t)ovf_src[i2] * (N_FEAT / 4) + q];
                    acc.x += hconv(u.x); acc.y += hconv(u.y);
                    acc.z += hconv(u.z); acc.w += hconv(u.w);
                }
            }
            out4[(size_t)(n0 + dl) * (N_FEAT / 4) + q] = acc;
        }
    }
}

extern "C" void kernel_launch(void* const* d_in, const int* in_sizes, int n_in,
                              void* d_out, int out_size, void* d_ws, size_t ws_size,
                              hipStream_t stream) {
    const float* x   = (const float*)d_in[0];
    const int*   ei  = (const int*)d_in[1];
    float*       out = (float*)d_out;

    const int n_edges = in_sizes[1] / 2;
    const int n_nodes = in_sizes[0] / N_FEAT;
    const int* src = ei;
    const int* dst = ei + n_edges;

    const int nbins = (n_nodes + NPB - 1) >> NPB_SHIFT;

    // workspace layout
    size_t off_binstream = 0;
    size_t off_xh        = off_binstream + (size_t)nbins * BINSLOT * sizeof(uint32_t);
    size_t off_ovf_src   = off_xh + (size_t)n_nodes * N_FEAT * sizeof(uint16_t);
    size_t off_ovf_dst   = off_ovf_src + (size_t)OVF_CAP * sizeof(uint32_t);
    size_t off_bincur    = off_ovf_dst + (size_t)OVF_CAP * sizeof(uint32_t);
    size_t off_ovf_cnt   = off_bincur + (size_t)nbins * sizeof(int);
    size_t ws_needed     = off_ovf_cnt + sizeof(int);

    if (nbins > MAX_BINS || n_nodes > (1 << 23) || ws_size < ws_needed) {
        // fallback: baseline atomic scatter (correct, ~177us, full f32)
        int threads = 256;
        zero_out<<<(out_size + threads - 1) / threads, threads, 0, stream>>>(out, out_size);
        long long total = (long long)n_edges * N_FEAT;
        mp_scatter_add<<<(int)((total + threads - 1) / threads), threads, 0, stream>>>(
            x, src, dst, out, n_edges);
        return;
    }

    char* ws = (char*)d_ws;
    uint32_t* binstream = (uint32_t*)(ws + off_binstream);
    ushort4*  xh4       = (ushort4*)(ws + off_xh);
    uint32_t* ovf_src   = (uint32_t*)(ws + off_ovf_src);
    uint32_t* ovf_dst   = (uint32_t*)(ws + off_ovf_dst);
    int*      bincur    = (int*)(ws + off_bincur);
    int*      ovf_cnt   = (int*)(ws + off_ovf_cnt);

    const int n4 = n_nodes * (N_FEAT / 4);
    convert_half<<<1024, 256, 0, stream>>>((const float4*)x, xh4, n4);

    init_bins<<<(nbins + 256) / 256, 256, 0, stream>>>(bincur, nbins, ovf_cnt);

    const int part_blocks = (n_edges + PART_CHUNK - 1) / PART_CHUNK;
    partition_bins<<<part_blocks, PART_THREADS, 0, stream>>>(
        src, dst, n_edges, bincur, binstream, ovf_src, ovf_dst, ovf_cnt, nbins);

    binsort_aggregate<<<nbins, FUSE_THREADS, 0, stream>>>(
        binstream, bincur, ovf_src, ovf_dst, ovf_cnt, xh4, out, n_nodes);
}

// Round 26
// 58.118 us; speedup vs baseline: 1.0946x; 1.0946x over previous
//
#include <hip/hip_runtime.h>
#include <stdint.h>

#define N_FEAT 32
#define NPB_SHIFT 8                   // 256 nodes per bin (best config)
#define NPB (1 << NPB_SHIFT)
#define MAX_BINS 512
#define BINSLOT 8192                  // fixed binstream slots per bin (avg load ~4096)
#define OVF_CAP 65536                 // overflow safety net (unused for this input)
#define PART_THREADS 1024
#define PART_CHUNK 3072               // edges per partition block (LDS-cached)
#define FUSE_THREADS 1024

// ---------- fallback path (baseline, known-correct, ~177us) ----------
__global__ void zero_out(float* __restrict__ out, int n) {
    int i = blockIdx.x * blockDim.x + threadIdx.x;
    if (i < n) out[i] = 0.0f;
}

__global__ void mp_scatter_add(const float* __restrict__ x,
                               const int* __restrict__ src,
                               const int* __restrict__ dst,
                               float* __restrict__ out,
                               int n_edges) {
    long long tid = (long long)blockIdx.x * blockDim.x + threadIdx.x;
    long long total = (long long)n_edges * N_FEAT;
    if (tid >= total) return;
    int e = (int)(tid >> 5);
    int f = (int)(tid & 31);
    atomicAdd(&out[(long long)dst[e] * N_FEAT + f],
              x[(long long)src[e] * N_FEAT + f]);
}

// ---------- fast path ----------
// R15: no cooperative grid.sync fusion (XCD coherence kills caching).
// R16/R17/R24/R25: fused kernel is NOT bound by sort, issue count, occupancy,
// or gather bytes. R26 theory: partition's scattered 4B binstream stores
// (~60 distinct lines per wave, R10 WRITE=3.7x buffer) are the hidden cost ->
// bin-sort the chunk in LDS and write contiguous per-bin bursts.

// K0: init per-bin cursors + overflow counter (ws is poisoned; must re-init).
__global__ void init_bins(int* __restrict__ bincur, int nbins,
                          int* __restrict__ ovf_cnt) {
    int t = blockIdx.x * blockDim.x + threadIdx.x;
    if (t < nbins) bincur[t] = t * BINSLOT;
    if (t == nbins) *ovf_cnt = 0;
}

// K1: partition edges into fixed-capacity bins. R26: chunk is bin-sorted in
// LDS first; global writes are per-bin contiguous bursts (coalesced).
__global__ void __launch_bounds__(PART_THREADS)
partition_bins(const int* __restrict__ src, const int* __restrict__ dst,
               int n_edges, int* __restrict__ bincur,
               uint32_t* __restrict__ binstream,
               uint32_t* __restrict__ ovf_src, uint32_t* __restrict__ ovf_dst,
               int* __restrict__ ovf_cnt, int nbins) {
    __shared__ uint32_t epack[PART_CHUNK];   // (src<<8)|dst_local
    __shared__ uint16_t ebin[PART_CHUNK];    // bin id (load order)
    __shared__ uint32_t srt[PART_CHUNK];     // bin-sorted edges
    __shared__ uint16_t sbin[PART_CHUNK];    // bin id (sorted order)
    __shared__ int cnt[MAX_BINS];            // counts -> local cursor
    __shared__ int lofs[MAX_BINS];           // local exclusive offset
    __shared__ int gofs[MAX_BINS];           // global base - local offset
    __shared__ int wsum[PART_THREADS / 64];  // per-wave scan totals
    const int t = threadIdx.x;
    const int beg = blockIdx.x * PART_CHUNK;
    const int end = min(beg + PART_CHUNK, n_edges);
    const int m = end - beg;

    for (int b = t; b < nbins; b += PART_THREADS) cnt[b] = 0;
    __syncthreads();
    // pass 1: load + count (src/dst read from HBM exactly once)
    for (int i = t; i < m; i += PART_THREADS) {
        int d = dst[beg + i];
        int s = src[beg + i];
        int b = d >> NPB_SHIFT;
        epack[i] = ((uint32_t)s << NPB_SHIFT) | (uint32_t)(d & (NPB - 1));
        ebin[i]  = (uint16_t)b;
        atomicAdd(&cnt[b], 1);               // LDS atomic
    }
    __syncthreads();
    // scan cnt[0..nbins) (nbins <= 512 <= 1024: single pass, all threads)
    int c = (t < nbins) ? cnt[t] : 0;
    int val = c;
#pragma unroll
    for (int off = 1; off < 64; off <<= 1) {
        int u = __shfl_up(val, (unsigned)off, 64);
        if ((t & 63) >= off) val += u;
    }
    if ((t & 63) == 63) wsum[t >> 6] = val;
    __syncthreads();
    {
        int w = t >> 6, prefix = 0;
#pragma unroll
        for (int k = 0; k < PART_THREADS / 64; ++k) if (k < w) prefix += wsum[k];
        val += prefix;                        // inclusive
    }
    if (t < nbins) {
        lofs[t] = val - c;                    // exclusive local offset
        int gbase = c ? atomicAdd(&bincur[t], c) : 0;  // one global atomic/bin
        gofs[t] = gbase - (val - c);
        cnt[t] = 0;                           // becomes local cursor
    }
    __syncthreads();
    // pass 2: rank-place into bin-sorted LDS buffer
    for (int i = t; i < m; i += PART_THREADS) {
        int b = ebin[i];
        int p = lofs[b] + atomicAdd(&cnt[b], 1);       // LDS atomic
        srt[p]  = epack[i];
        sbin[p] = (uint16_t)b;
    }
    __syncthreads();
    // pass 3: burst write — consecutive p within a bin -> consecutive gp
    for (int p = t; p < m; p += PART_THREADS) {
        int b = sbin[p];
        uint32_t e = srt[p];
        int gp = gofs[b] + p;
        if (gp < (b + 1) * BINSLOT) {
            binstream[gp] = e;                         // coalesced burst
        } else {                                       // overflow net (never here)
            int o = atomicAdd(ovf_cnt, 1);
            if (o < OVF_CAP) {
                ovf_src[o] = e >> NPB_SHIFT;
                ovf_dst[o] = ((uint32_t)b << NPB_SHIFT) | (e & (NPB - 1));
            }
        }
    }
}

// K2 (FUSED sort+aggregate): one block per 256-node bin (unchanged, proven
// 61.6us config: NT binstream read, ebuf single-read, wave-shfl scan,
// 16-wide unmasked main loop + 4-wide tail, f32 float4 gathers).
__global__ void __launch_bounds__(FUSE_THREADS)
binsort_aggregate(const uint32_t* __restrict__ binstream,
                  const int* __restrict__ bincur,
                  const uint32_t* __restrict__ ovf_src,
                  const uint32_t* __restrict__ ovf_dst,
                  const int* __restrict__ ovf_cnt,
                  const float* __restrict__ x,
                  float* __restrict__ out, int n_nodes) {
    __shared__ uint32_t ebuf[BINSLOT];     // 32 KB
    __shared__ uint32_t srtd[BINSLOT];     // 32 KB
    __shared__ int hist[NPB];
    __shared__ int sc[NPB];
    __shared__ int lcur[NPB];
    __shared__ int wsum[4];
    const int b = blockIdx.x;
    const int n0 = b << NPB_SHIFT;
    const int nn = min(NPB, n_nodes - n0);
    const int binstart = b * BINSLOT;
    const int cnt = min(bincur[b] - binstart, BINSLOT);
    const int novf = *ovf_cnt;             // 0 in practice
    const int t = threadIdx.x;
    const int g  = t >> 5;
    const int l  = t & 31;
    const int e4 = l >> 3;
    const int q  = l & 7;
    const float4* __restrict__ x4 = (const float4*)x;
    float4* __restrict__ out4 = (float4*)out;

    if (t < NPB) { hist[t] = 0; lcur[t] = 0; }
    __syncthreads();
    for (int i = t; i < cnt; i += FUSE_THREADS) {
        uint32_t e = __builtin_nontemporal_load(&binstream[binstart + i]);
        ebuf[i] = e;
        atomicAdd(&hist[e & (NPB - 1)], 1);
    }
    __syncthreads();

    int vin = 0, val = 0;
    if (t < NPB) {
        vin = hist[t];
        val = vin;
#pragma unroll
        for (int off = 1; off < 64; off <<= 1) {
            int u = __shfl_up(val, (unsigned)off, 64);
            if ((t & 63) >= off) val += u;
        }
        if ((t & 63) == 63) wsum[t >> 6] = val;
    }
    __syncthreads();
    if (t < NPB) {
        int w = t >> 6, prefix = 0;
#pragma unroll
        for (int k = 0; k < 3; ++k) if (k < w) prefix += wsum[k];
        val += prefix;
        sc[t] = val;
        hist[t] = val - vin;
    }
    __syncthreads();

    for (int i = t; i < cnt; i += FUSE_THREADS) {
        uint32_t e = ebuf[i];
        int dl = (int)(e & (NPB - 1));
        int p = hist[dl] + atomicAdd(&lcur[dl], 1);
        srtd[p] = e >> NPB_SHIFT;
    }
    __syncthreads();

    for (int dl = g; dl < nn; dl += 32) {
        int beg = hist[dl];
        int end = sc[dl];
        float4 acc = make_float4(0.f, 0.f, 0.f, 0.f);
        int i = beg;
        for (; i + 16 <= end; i += 16) {
#pragma unroll
            for (int k = 0; k < 4; ++k) {
                uint32_t s = srtd[i + k * 4 + e4];
                float4 vv = x4[(size_t)s * (N_FEAT / 4) + q];
                acc.x += vv.x; acc.y += vv.y; acc.z += vv.z; acc.w += vv.w;
            }
        }
        for (; i < end; i += 4) {
            int j = i + e4;
            bool ok = j < end;
            uint32_t s = srtd[ok ? j : i];
            float4 vv = x4[(size_t)s * (N_FEAT / 4) + q];
            float mk = ok ? 1.0f : 0.0f;
            acc.x = fmaf(vv.x, mk, acc.x);
            acc.y = fmaf(vv.y, mk, acc.y);
            acc.z = fmaf(vv.z, mk, acc.z);
            acc.w = fmaf(vv.w, mk, acc.w);
        }
        acc.x += __shfl_xor(acc.x, 8);  acc.y += __shfl_xor(acc.y, 8);
        acc.z += __shfl_xor(acc.z, 8);  acc.w += __shfl_xor(acc.w, 8);
        acc.x += __shfl_xor(acc.x, 16); acc.y += __shfl_xor(acc.y, 16);
        acc.z += __shfl_xor(acc.z, 16); acc.w += __shfl_xor(acc.w, 16);
        if (e4 == 0) {
            for (int i2 = 0; i2 < novf; ++i2) {
                uint32_t od = ovf_dst[i2];
                if ((int)(od >> NPB_SHIFT) == b && (int)(od & (NPB - 1)) == dl) {
                    float4 vv = x4[(size_t)ovf_src[i2] * (N_FEAT / 4) + q];
                    acc.x += vv.x; acc.y += vv.y; acc.z += vv.z; acc.w += vv.w;
                }
            }
            out4[(size_t)(n0 + dl) * (N_FEAT / 4) + q] = acc;
        }
    }
}

extern "C" void kernel_launch(void* const* d_in, const int* in_sizes, int n_in,
                              void* d_out, int out_size, void* d_ws, size_t ws_size,
                              hipStream_t stream) {
    const float* x   = (const float*)d_in[0];
    const int*   ei  = (const int*)d_in[1];
    float*       out = (float*)d_out;

    const int n_edges = in_sizes[1] / 2;
    const int n_nodes = in_sizes[0] / N_FEAT;
    const int* src = ei;
    const int* dst = ei + n_edges;

    const int nbins = (n_nodes + NPB - 1) >> NPB_SHIFT;

    // workspace layout
    size_t off_binstream = 0;
    size_t off_ovf_src   = off_binstream + (size_t)nbins * BINSLOT * sizeof(uint32_t);
    size_t off_ovf_dst   = off_ovf_src + (size_t)OVF_CAP * sizeof(uint32_t);
    size_t off_bincur    = off_ovf_dst + (size_t)OVF_CAP * sizeof(uint32_t);
    size_t off_ovf_cnt   = off_bincur + (size_t)nbins * sizeof(int);
    size_t ws_needed     = off_ovf_cnt + sizeof(int);

    if (nbins > MAX_BINS || n_nodes > (1 << 23) || ws_size < ws_needed) {
        // fallback: baseline atomic scatter (correct, ~177us)
        int threads = 256;
        zero_out<<<(out_size + threads - 1) / threads, threads, 0, stream>>>(out, out_size);
        long long total = (long long)n_edges * N_FEAT;
        mp_scatter_add<<<(int)((total + threads - 1) / threads), threads, 0, stream>>>(
            x, src, dst, out, n_edges);
        return;
    }

    char* ws = (char*)d_ws;
    uint32_t* binstream = (uint32_t*)(ws + off_binstream);
    uint32_t* ovf_src   = (uint32_t*)(ws + off_ovf_src);
    uint32_t* ovf_dst   = (uint32_t*)(ws + off_ovf_dst);
    int*      bincur    = (int*)(ws + off_bincur);
    int*      ovf_cnt   = (int*)(ws + off_ovf_cnt);

    init_bins<<<(nbins + 256) / 256, 256, 0, stream>>>(bincur, nbins, ovf_cnt);

    const int part_blocks = (n_edges + PART_CHUNK - 1) / PART_CHUNK;
    partition_bins<<<part_blocks, PART_THREADS, 0, stream>>>(
        src, dst, n_edges, bincur, binstream, ovf_src, ovf_dst, ovf_cnt, nbins);

    binsort_aggregate<<<nbins, FUSE_THREADS, 0, stream>>>(
        binstream, bincur, ovf_src, ovf_dst, ovf_cnt, x, out, n_nodes);
}